// Round 6
// baseline (103.195 us; speedup 1.0000x reference)
//
#include <hip/hip_runtime.h>
#include <math.h>

#define NQ 6
#define BLK 1024
#define HID 256
#define INDIM 784

#define PW1 0.001f
#define PW2 0.01f
constexpr float WO1 = 1.f - 4.f * PW1 / 3.f;   // dep1 Bloch shrink
constexpr float WO2 = 1.f - 4.f * PW2 / 3.f;   // dep2 Bloch shrink
constexpr float WOc = WO1 * WO2;               // combined mid-circuit dep

// ---------- compile-time CNOT-ring tables (inverse map + sign) ----------
// Pauli string: wire w -> bits (x_w at 2w+1, z_w at 2w). Code q=(x<<1)|z: 0=I,1=Z,2=X,3=Y.
// CNOT(c->t): sign ^= x_c z_t (x_t ^ z_c ^ 1); x_t ^= x_c; z_c ^= z_t.
// U^dag P U for ring U = C5..C0 (C0 first): conjugate by C5 first ... C0 last.
struct alignas(16) RingTabs { int t[3][4096]; };
constexpr RingTabs make_ring_tabs() {
    RingTabs R{};
    for (int ri = 0; ri < 3; ++ri) {
        int r = ri + 1;
        for (int v = 0; v < 4096; ++v) {
            int x[6], z[6];
            for (int w = 0; w < 6; ++w) { x[w] = (v >> (2 * w + 1)) & 1; z[w] = (v >> (2 * w)) & 1; }
            int sgn = 0;
            for (int i = 5; i >= 0; --i) {
                int c = i, tg = (i + r) % 6;
                sgn ^= x[c] & z[tg] & (x[tg] ^ z[c] ^ 1);
                x[tg] ^= x[c];
                z[c]  ^= z[tg];
            }
            int s = 0;
            for (int w = 0; w < 6; ++w) s |= (x[w] << (2 * w + 1)) | (z[w] << (2 * w));
            R.t[ri][v] = s | (sgn << 31);
        }
    }
    return R;
}
static __device__ const RingTabs RT = make_ring_tabs();

// LDS bank swizzle (same as round 5): injects n[7:6]^n[11:10] into bank bits [4:3].
__device__ __forceinline__ int swz(int n) {
    return n ^ ((((n >> 6) ^ (n >> 10)) & 3) << 3);
}

// DPP quad broadcasts (quad lane k's value), pure VALU
template<int CTRL>
__device__ __forceinline__ float qb(float v) {
    int r = __builtin_amdgcn_update_dpp(0, __builtin_bit_cast(int, v), CTRL, 0xF, 0xF, true);
    return __builtin_bit_cast(float, r);
}
// ds_swizzle with compile-time pattern (set-bits broadcast, crossbar, no banks)
template<int OFF>
__device__ __forceinline__ float swzl(float v) {
    return __builtin_bit_cast(float, __builtin_amdgcn_ds_swizzle(__builtin_bit_cast(int, v), OFF));
}

// Gate on the register wire (e-index is that wire's Pauli code; 1=Z,2=X,3=Y)
__device__ __forceinline__ void rot_reg(float e[4], float4 rZ, float4 rX, float4 rY) {
    float X = e[2], Y = e[3], Z = e[1];
    e[2] = fmaf(rX.x, X, fmaf(rX.y, Y, rX.z * Z));
    e[3] = fmaf(rY.x, X, fmaf(rY.y, Y, rY.z * Z));
    e[1] = fmaf(rZ.x, X, fmaf(rZ.y, Y, rZ.z * Z));
}
// Gate on wire at lane bits [1:0] (cf = row for own code: (cX,cY,cZ,keep))
__device__ __forceinline__ void rot_q1(float e[4], float4 cf) {
    #pragma unroll
    for (int j = 0; j < 4; ++j) {
        float vZ = qb<0x55>(e[j]);   // quad lane 1 (Z)
        float vX = qb<0xAA>(e[j]);   // quad lane 2 (X)
        float vY = qb<0xFF>(e[j]);   // quad lane 3 (Y)
        e[j] = fmaf(cf.x, vX, fmaf(cf.y, vY, fmaf(cf.z, vZ, cf.w * e[j])));
    }
}
// Gate on wire at lane bits [3:2]: ds_swizzle src = (lane & 0x13) | (c<<2)
__device__ __forceinline__ void rot_q2(float e[4], float4 cf) {
    #pragma unroll
    for (int j = 0; j < 4; ++j) {
        float vZ = swzl<0x093>(e[j]);  // c=1 (Z)
        float vX = swzl<0x113>(e[j]);  // c=2 (X)
        float vY = swzl<0x193>(e[j]);  // c=3 (Y)
        e[j] = fmaf(cf.x, vX, fmaf(cf.y, vY, fmaf(cf.z, vZ, cf.w * e[j])));
    }
}
// Gate on wire at lane bits [5:4]: ds_bpermute src = (lane & 0xF) | (c<<4)
__device__ __forceinline__ void rot_q3(float e[4], float4 cf, int lane) {
    int s1 = (lane & 15) | 16, s2 = (lane & 15) | 32, s3 = (lane & 15) | 48;
    #pragma unroll
    for (int j = 0; j < 4; ++j) {
        float vZ = __shfl(e[j], s1, 64);
        float vX = __shfl(e[j], s2, 64);
        float vY = __shfl(e[j], s3, 64);
        e[j] = fmaf(cf.x, vX, fmaf(cf.y, vY, fmaf(cf.z, vZ, cf.w * e[j])));
    }
}

// Pauli index v = (q5<<10)|(q4<<8)|(q3<<6)|(q2<<4)|(q1<<2)|q0; wire w code at bits [2w+1:2w].
// Stage A (wires 0-3, intra-wave): wave = (q5,q4), lane = (q3,q2,q1), regs = q0.
// Stage B (wires 4-5, exchange): regs = q4, lane[1:0] = q5, (q3..q0) = (wave<<4)|lane[5:2].

__global__ __launch_bounds__(BLK)
void nqm_kernel(const float* __restrict__ x, const float* __restrict__ W1,
                const float* __restrict__ b1, const float* __restrict__ ln_g,
                const float* __restrict__ ln_b, const float* __restrict__ W2,
                const float* __restrict__ b2, const float* __restrict__ shared_w,
                const float* __restrict__ task_w, const float* __restrict__ Wp,
                const float* __restrict__ bp, float* __restrict__ out)
{
    __shared__ __align__(16) float dmA[4096];    // 16 KB Pauli coefficients (buffer A)
    __shared__ __align__(16) float dmB[4096];    // 16 KB (buffer B)
    __shared__ float4 xrow[INDIM / 4];
    __shared__ float hpart[1024];
    __shared__ __align__(16) float4 Mlane[30][4]; // per gate: row for own code (cX,cY,cZ,keep)
    __shared__ float bloch[NQ][4];               // initial per-qubit coeffs [1, WO1*c, WO1*s, 0]
    __shared__ float red[4], red2[4];
    __shared__ float zpart[4][8];
    __shared__ float bcast[2];
    __shared__ float evs[8];

    const int tid = threadIdx.x;
    const int b = blockIdx.x;
    const int wv = tid >> 6;
    const int lane = tid & 63;

    // ---------------- encoder: h = relu(x @ W1^T + b1) ----------------
    if (tid < INDIM / 4) xrow[tid] = ((const float4*)(x + (size_t)b * INDIM))[tid];
    __syncthreads();

    {   // 4 threads per hidden unit, 49 float4 each
        const int u = tid & 255, p = tid >> 8;
        const float4* w1v = (const float4*)(W1 + (size_t)u * INDIM) + p * 49;
        const float4* xv4 = xrow + p * 49;
        float acc = 0.0f;
        #pragma unroll 7
        for (int k = 0; k < 49; ++k) {
            float4 wvv = w1v[k];
            float4 xv = xv4[k];
            acc = fmaf(wvv.x, xv.x, acc);
            acc = fmaf(wvv.y, xv.y, acc);
            acc = fmaf(wvv.z, xv.z, acc);
            acc = fmaf(wvv.w, xv.w, acc);
        }
        hpart[p * 256 + u] = acc;
    }
    __syncthreads();

    float h = 0.0f;
    if (tid < 256) {
        h = hpart[tid] + hpart[256 + tid] + hpart[512 + tid] + hpart[768 + tid] + b1[tid];
        h = fmaxf(h, 0.0f);
        float s = h, s2 = h * h;
        #pragma unroll
        for (int off = 32; off > 0; off >>= 1) {
            s  += __shfl_down(s, off, 64);
            s2 += __shfl_down(s2, off, 64);
        }
        if (lane == 0) { red[tid >> 6] = s; red2[tid >> 6] = s2; }
    }
    __syncthreads();
    if (tid == 0) {
        float ts  = red[0] + red[1] + red[2] + red[3];
        float ts2 = red2[0] + red2[1] + red2[2] + red2[3];
        float mu  = ts * (1.0f / HID);
        float var = ts2 * (1.0f / HID) - mu * mu;
        bcast[0] = mu;
        bcast[1] = rsqrtf(var + 1e-5f);
    }
    __syncthreads();
    if (tid < 256) {
        float hnj = (h - bcast[0]) * bcast[1] * ln_g[tid] + ln_b[tid];
        float p[NQ];
        #pragma unroll
        for (int i = 0; i < NQ; ++i) p[i] = hnj * W2[i * HID + tid];
        #pragma unroll
        for (int off = 32; off > 0; off >>= 1) {
            #pragma unroll
            for (int i = 0; i < NQ; ++i) p[i] += __shfl_down(p[i], off, 64);
        }
        if (lane == 0) {
            #pragma unroll
            for (int i = 0; i < NQ; ++i) zpart[tid >> 6][i] = p[i];
        }
    }
    __syncthreads();

    // ------------- gate SO(3) matrices + initial Bloch vectors -------------
    if (tid < NQ) {
        float z = zpart[0][tid] + zpart[1][tid] + zpart[2][tid] + zpart[3][tid] + b2[tid];
        z = tanhf(z);
        float sn, c;
        sincosf(z * 3.14159265358979323846f, &sn, &c);
        bloch[tid][0] = 1.0f;
        bloch[tid][1] = WO1 * c;    // Z
        bloch[tid][2] = WO1 * sn;   // X
        bloch[tid][3] = 0.0f;       // Y
    } else if (tid < 36) {          // threads 6..35 -> gates 0..29
        int g = tid - NQ;
        int layer = g / NQ;
        int wire = g % NQ;
        const float* w = (layer < 3) ? (shared_w + (layer * NQ + wire) * 3)
                                     : (task_w + ((layer - 3) * NQ + wire) * 3);
        float phi = w[0], theta = w[1], omega = w[2];
        float sf, cf_, st, ct, so, co;
        sincosf(phi, &sf, &cf_);
        sincosf(theta, &st, &ct);
        sincosf(omega, &so, &co);
        // M = Mz(omega) * My(theta) * Mz(phi)
        float M00 = co * ct * cf_ - so * sf;
        float M01 = -co * ct * sf - so * cf_;
        float M02 = co * st;
        float M10 = so * ct * cf_ + co * sf;
        float M11 = -so * ct * sf + co * cf_;
        float M12 = so * st;
        float M20 = -st * cf_;
        float M21 = st * sf;
        float M22 = ct;
        float f = (layer == 3) ? ((wire < 5) ? WOc : WO1) : 1.0f;   // mid-circuit deps baked
        Mlane[g][0] = make_float4(0.f, 0.f, 0.f, 1.f);              // I: keep
        Mlane[g][1] = make_float4(f * M20, f * M21, f * M22, 0.f);  // Z row
        Mlane[g][2] = make_float4(f * M00, f * M01, f * M02, 0.f);  // X row
        Mlane[g][3] = make_float4(f * M10, f * M11, f * M12, 0.f);  // Y row
    }

    // per-thread constants
    const int q1 = lane & 3, q2 = (lane >> 2) & 3, q3 = (lane >> 4) & 3;
    const int q4 = wv & 3, q5 = wv >> 2;
    // stage-B base index: v' = (lane[1:0]<<10) | (q4=j)<<8 | (wv<<4) | lane[5:2]
    const int baseB = ((lane & 3) << 10) | (wv << 4) | (lane >> 2);
    const int rtab[4] = {0, 1, 2, 0};
    __syncthreads();

    // ---------------- 5 entangling layers: stage A + stage B ----------------
    for (int l = 0; l < 5; ++l) {
        const int g0 = l * 6;
        float e[4];

        // ==== stage A: wires 0..3, intra-wave, reads dmA (or product state), writes dmB ====
        if (l == 0) {
            float A = bloch[1][q1] * bloch[2][q2] * bloch[3][q3] * bloch[4][q4] * bloch[5][q5];
            e[0] = A * bloch[0][0];
            e[1] = A * bloch[0][1];
            e[2] = A * bloch[0][2];
            e[3] = A * bloch[0][3];
        } else {
            // gather prev layer's CNOT ring (inverse + sign) from compile-time table
            const int4 te = *(const int4*)&RT.t[rtab[l - 1]][tid << 2];
            float v0 = dmA[swz(te.x & 4095)];
            float v1 = dmA[swz(te.y & 4095)];
            float v2 = dmA[swz(te.z & 4095)];
            float v3 = dmA[swz(te.w & 4095)];
            e[0] = __int_as_float(__float_as_int(v0) ^ (te.x & 0x80000000));
            e[1] = __int_as_float(__float_as_int(v1) ^ (te.y & 0x80000000));
            e[2] = __int_as_float(__float_as_int(v2) ^ (te.z & 0x80000000));
            e[3] = __int_as_float(__float_as_int(v3) ^ (te.w & 0x80000000));
        }
        rot_reg(e, Mlane[g0 + 0][1], Mlane[g0 + 0][2], Mlane[g0 + 0][3]);  // wire0 (regs)
        rot_q1(e, Mlane[g0 + 1][q1]);                                      // wire1 (DPP)
        rot_q2(e, Mlane[g0 + 2][q2]);                                      // wire2 (swizzle)
        rot_q3(e, Mlane[g0 + 3][q3], lane);                                // wire3 (bpermute)
        *(float4*)&dmB[swz(tid << 2)] = make_float4(e[0], e[1], e[2], e[3]);
        __syncthreads();

        // ==== stage B: wires 4..5, exchange pass, reads dmB, writes dmA ====
        e[0] = dmB[swz(baseB)];
        e[1] = dmB[swz(baseB + 256)];
        e[2] = dmB[swz(baseB + 512)];
        e[3] = dmB[swz(baseB + 768)];
        rot_reg(e, Mlane[g0 + 4][1], Mlane[g0 + 4][2], Mlane[g0 + 4][3]);  // wire4 (regs=q4)
        rot_q1(e, Mlane[g0 + 5][lane & 3]);                                // wire5 (DPP, q5=lane[1:0])
        dmA[swz(baseB)]       = e[0];
        dmA[swz(baseB + 256)] = e[1];
        dmA[swz(baseB + 512)] = e[2];
        dmA[swz(baseB + 768)] = e[3];
        __syncthreads();
    }

    // ---- readout: fold final ring (r=2 -> table 1) + final dep1 + linear head ----
    if (tid < NQ) {
        int e = RT.t[1][1 << (2 * tid)];            // Z on wire tid
        float v = dmA[swz(e & 4095)];
        v = __int_as_float(__float_as_int(v) ^ (e & 0x80000000));
        evs[tid] = WO1 * v;
    }
    __syncthreads();
    if (tid < 2) {
        float o = bp[tid];
        #pragma unroll
        for (int i = 0; i < NQ; ++i) o = fmaf(evs[i], Wp[tid * NQ + i], o);
        out[b * 2 + tid] = o;
    }
}

extern "C" void kernel_launch(void* const* d_in, const int* in_sizes, int n_in,
                              void* d_out, int out_size, void* d_ws, size_t ws_size,
                              hipStream_t stream) {
    (void)in_sizes; (void)n_in; (void)d_ws; (void)ws_size; (void)out_size;
    const float* x        = (const float*)d_in[0];
    const float* W1       = (const float*)d_in[1];
    const float* b1       = (const float*)d_in[2];
    const float* ln_g     = (const float*)d_in[3];
    const float* ln_b     = (const float*)d_in[4];
    const float* W2       = (const float*)d_in[5];
    const float* b2       = (const float*)d_in[6];
    const float* shared_w = (const float*)d_in[7];
    const float* task_w   = (const float*)d_in[8];
    const float* Wp       = (const float*)d_in[9];
    const float* bp       = (const float*)d_in[10];
    float* out = (float*)d_out;

    hipLaunchKernelGGL(nqm_kernel, dim3(256), dim3(BLK), 0, stream,
                       x, W1, b1, ln_g, ln_b, W2, b2, shared_w, task_w, Wp, bp, out);
}

// Round 8
// 95.531 us; speedup vs baseline: 1.0802x; 1.0802x over previous
//
#include <hip/hip_runtime.h>
#include <math.h>

#define NQ 6
#define BLK 1024
#define HID 256
#define INDIM 784

#define PW1 0.001f
#define PW2 0.01f
constexpr float WO1 = 1.f - 4.f * PW1 / 3.f;   // dep1 Bloch shrink
constexpr float WO2 = 1.f - 4.f * PW2 / 3.f;   // dep2 Bloch shrink
constexpr float WOc = WO1 * WO2;               // combined mid-circuit dep

// ---------- compile-time CNOT-ring tables (inverse map + sign) ----------
// Pauli string: wire w -> bits (x_w at 2w+1, z_w at 2w). Code q=(x<<1)|z: 0=I,1=Z,2=X,3=Y.
// CNOT(c->t): sign ^= x_c z_t (x_t ^ z_c ^ 1); x_t ^= x_c; z_c ^= z_t.
// U^dag P U for ring U = C5..C0 (C0 first): conjugate by C5 first ... C0 last.
struct alignas(16) RingTabs { int t[3][4096]; };
constexpr RingTabs make_ring_tabs() {
    RingTabs R{};
    for (int ri = 0; ri < 3; ++ri) {
        int r = ri + 1;
        for (int v = 0; v < 4096; ++v) {
            int x[6], z[6];
            for (int w = 0; w < 6; ++w) { x[w] = (v >> (2 * w + 1)) & 1; z[w] = (v >> (2 * w)) & 1; }
            int sgn = 0;
            for (int i = 5; i >= 0; --i) {
                int c = i, tg = (i + r) % 6;
                sgn ^= x[c] & z[tg] & (x[tg] ^ z[c] ^ 1);
                x[tg] ^= x[c];
                z[c]  ^= z[tg];
            }
            int s = 0;
            for (int w = 0; w < 6; ++w) s |= (x[w] << (2 * w + 1)) | (z[w] << (2 * w));
            R.t[ri][v] = s | (sgn << 31);
        }
    }
    return R;
}
static __device__ const RingTabs RT = make_ring_tabs();

// LDS bank swizzle: injects n[7:6]^n[11:10] into bank bits [4:3].
__device__ __forceinline__ int swz(int n) {
    return n ^ ((((n >> 6) ^ (n >> 10)) & 3) << 3);
}

// DPP quad broadcasts (quad lane k's value), pure VALU
template<int CTRL>
__device__ __forceinline__ float qb(float v) {
    int r = __builtin_amdgcn_update_dpp(0, __builtin_bit_cast(int, v), CTRL, 0xF, 0xF, true);
    return __builtin_bit_cast(float, r);
}
// ds_swizzle with compile-time pattern
template<int OFF>
__device__ __forceinline__ float swzl(float v) {
    return __builtin_bit_cast(float, __builtin_amdgcn_ds_swizzle(__builtin_bit_cast(int, v), OFF));
}

__device__ __forceinline__ void rot_reg(float e[4], float4 rZ, float4 rX, float4 rY) {
    float X = e[2], Y = e[3], Z = e[1];
    e[2] = fmaf(rX.x, X, fmaf(rX.y, Y, rX.z * Z));
    e[3] = fmaf(rY.x, X, fmaf(rY.y, Y, rY.z * Z));
    e[1] = fmaf(rZ.x, X, fmaf(rZ.y, Y, rZ.z * Z));
}
__device__ __forceinline__ void rot_q1(float e[4], float4 cf) {
    #pragma unroll
    for (int j = 0; j < 4; ++j) {
        float vZ = qb<0x55>(e[j]);
        float vX = qb<0xAA>(e[j]);
        float vY = qb<0xFF>(e[j]);
        e[j] = fmaf(cf.x, vX, fmaf(cf.y, vY, fmaf(cf.z, vZ, cf.w * e[j])));
    }
}
__device__ __forceinline__ void rot_q2(float e[4], float4 cf) {
    #pragma unroll
    for (int j = 0; j < 4; ++j) {
        float vZ = swzl<0x093>(e[j]);
        float vX = swzl<0x113>(e[j]);
        float vY = swzl<0x193>(e[j]);
        e[j] = fmaf(cf.x, vX, fmaf(cf.y, vY, fmaf(cf.z, vZ, cf.w * e[j])));
    }
}
__device__ __forceinline__ void rot_q3(float e[4], float4 cf, int lane) {
    int s1 = (lane & 15) | 16, s2 = (lane & 15) | 32, s3 = (lane & 15) | 48;
    #pragma unroll
    for (int j = 0; j < 4; ++j) {
        float vZ = __shfl(e[j], s1, 64);
        float vX = __shfl(e[j], s2, 64);
        float vY = __shfl(e[j], s3, 64);
        e[j] = fmaf(cf.x, vX, fmaf(cf.y, vY, fmaf(cf.z, vZ, cf.w * e[j])));
    }
}

// ================= kernel A: tiled GEMM partials hp[s][b][u] =================
// 256 blocks = 64 tiles (32b x 32u) x 4 k-splits (196). 256 threads, 2x2 reg tile.
__global__ __launch_bounds__(256)
void enc_gemm(const float* __restrict__ x, const float* __restrict__ W1,
              float* __restrict__ hp)
{
    __shared__ float xsT[196][32];   // [k][b] transposed
    __shared__ float wsT[196][32];   // [k][u] transposed
    const int tid = threadIdx.x;
    const int bid = blockIdx.x;
    const int tile = bid >> 2, s = bid & 3;
    const int bb = (tile >> 3) * 32, bu = (tile & 7) * 32;
    const int k0 = s * 196;

    // stage: 2 matrices x 32 rows x 49 float4 = 3136 float4 total.
    // i -> (r = i&31, chunk cb = i>>5); cb 0..48 = x, 49..97 = W1.
    // LDS writes: lanes in a wave have 32 distinct r -> banks 0..31, 2-way (free).
    for (int i = tid; i < 3136; i += 256) {
        int r = i & 31;
        int cb = i >> 5;
        int m = (cb >= 49);
        int c = cb - m * 49;
        const float* src = m ? (W1 + (size_t)(bu + r) * INDIM + k0 + 4 * c)
                             : (x  + (size_t)(bb + r) * INDIM + k0 + 4 * c);
        float4 v = *(const float4*)src;
        float (*dst)[32] = m ? wsT : xsT;
        dst[4 * c + 0][r] = v.x;
        dst[4 * c + 1][r] = v.y;
        dst[4 * c + 2][r] = v.z;
        dst[4 * c + 3][r] = v.w;
    }
    __syncthreads();

    const int tx = tid & 15, ty = tid >> 4;
    float a00 = 0.f, a01 = 0.f, a10 = 0.f, a11 = 0.f;
    #pragma unroll 4
    for (int k = 0; k < 196; ++k) {
        float2 xv = *(const float2*)&xsT[k][2 * ty];
        float2 wv = *(const float2*)&wsT[k][2 * tx];
        a00 = fmaf(xv.x, wv.x, a00);
        a01 = fmaf(xv.x, wv.y, a01);
        a10 = fmaf(xv.y, wv.x, a10);
        a11 = fmaf(xv.y, wv.y, a11);
    }
    float* o = hp + (size_t)s * 65536 + (size_t)(bb + 2 * ty) * 256 + bu + 2 * tx;
    o[0] = a00; o[1] = a01;
    o[256] = a10; o[257] = a11;
}

// ================= kernel B: LN + z + circuit (Pauli domain) =================
// Pauli index v = (q5<<10)|(q4<<8)|(q3<<6)|(q2<<4)|(q1<<2)|q0.
// Stage A (wires 0-3, intra-wave): wave=(q5,q4), lane=(q3,q2,q1), regs=q0.
// Stage B (wires 4-5): regs=q4, lane[1:0]=q5, rest=(wave<<4)|lane[5:2].
__global__ __launch_bounds__(BLK)
void nqm_kernel(const float* __restrict__ hp, const float* __restrict__ b1,
                const float* __restrict__ ln_g, const float* __restrict__ ln_b,
                const float* __restrict__ W2, const float* __restrict__ b2,
                const float* __restrict__ shared_w, const float* __restrict__ task_w,
                const float* __restrict__ Wp, const float* __restrict__ bp,
                float* __restrict__ out)
{
    __shared__ __align__(16) float dmA[4096];
    __shared__ __align__(16) float dmB[4096];
    __shared__ __align__(16) float4 Mlane[30][4];
    __shared__ float bloch[NQ][4];
    __shared__ float red[4], red2[4];
    __shared__ float zpart[4][8];
    __shared__ float bcast[2];
    __shared__ float evs[8];

    const int tid = threadIdx.x;
    const int b = blockIdx.x;
    const int wv = tid >> 6;
    const int lane = tid & 63;

    // ---------------- h = relu(sum hp + b1); LayerNorm; z partials ----------------
    float h = 0.0f;
    if (tid < 256) {
        const float* hb = hp + (size_t)b * 256 + tid;
        h = hb[0] + hb[65536] + hb[131072] + hb[196608] + b1[tid];
        h = fmaxf(h, 0.0f);
        float s = h, s2 = h * h;
        #pragma unroll
        for (int off = 32; off > 0; off >>= 1) {
            s  += __shfl_down(s, off, 64);
            s2 += __shfl_down(s2, off, 64);
        }
        if (lane == 0) { red[tid >> 6] = s; red2[tid >> 6] = s2; }
    }
    __syncthreads();
    if (tid == 0) {
        float ts  = red[0] + red[1] + red[2] + red[3];
        float ts2 = red2[0] + red2[1] + red2[2] + red2[3];
        float mu  = ts * (1.0f / HID);
        float var = ts2 * (1.0f / HID) - mu * mu;
        bcast[0] = mu;
        bcast[1] = rsqrtf(var + 1e-5f);
    }
    __syncthreads();
    if (tid < 256) {
        float hnj = (h - bcast[0]) * bcast[1] * ln_g[tid] + ln_b[tid];
        float p[NQ];
        #pragma unroll
        for (int i = 0; i < NQ; ++i) p[i] = hnj * W2[i * HID + tid];
        #pragma unroll
        for (int off = 32; off > 0; off >>= 1) {
            #pragma unroll
            for (int i = 0; i < NQ; ++i) p[i] += __shfl_down(p[i], off, 64);
        }
        if (lane == 0) {
            #pragma unroll
            for (int i = 0; i < NQ; ++i) zpart[tid >> 6][i] = p[i];
        }
    }
    __syncthreads();

    // ------------- gate SO(3) matrices + initial Bloch vectors -------------
    if (tid < NQ) {
        float z = zpart[0][tid] + zpart[1][tid] + zpart[2][tid] + zpart[3][tid] + b2[tid];
        z = tanhf(z);
        float sn, c;
        sincosf(z * 3.14159265358979323846f, &sn, &c);
        bloch[tid][0] = 1.0f;
        bloch[tid][1] = WO1 * c;    // Z
        bloch[tid][2] = WO1 * sn;   // X
        bloch[tid][3] = 0.0f;       // Y
    } else if (tid < 36) {          // threads 6..35 -> gates 0..29
        int g = tid - NQ;
        int layer = g / NQ;
        int wire = g % NQ;
        const float* w = (layer < 3) ? (shared_w + (layer * NQ + wire) * 3)
                                     : (task_w + ((layer - 3) * NQ + wire) * 3);
        float phi = w[0], theta = w[1], omega = w[2];
        float sf, cf_, st, ct, so, co;
        sincosf(phi, &sf, &cf_);
        sincosf(theta, &st, &ct);
        sincosf(omega, &so, &co);
        float M00 = co * ct * cf_ - so * sf;
        float M01 = -co * ct * sf - so * cf_;
        float M02 = co * st;
        float M10 = so * ct * cf_ + co * sf;
        float M11 = -so * ct * sf + co * cf_;
        float M12 = so * st;
        float M20 = -st * cf_;
        float M21 = st * sf;
        float M22 = ct;
        float f = (layer == 3) ? ((wire < 5) ? WOc : WO1) : 1.0f;   // mid-circuit deps baked
        Mlane[g][0] = make_float4(0.f, 0.f, 0.f, 1.f);
        Mlane[g][1] = make_float4(f * M20, f * M21, f * M22, 0.f);
        Mlane[g][2] = make_float4(f * M00, f * M01, f * M02, 0.f);
        Mlane[g][3] = make_float4(f * M10, f * M11, f * M12, 0.f);
    }

    const int q1 = lane & 3, q2 = (lane >> 2) & 3, q3 = (lane >> 4) & 3;
    const int q4 = wv & 3, q5 = wv >> 2;
    const int baseB = ((lane & 3) << 10) | (wv << 4) | (lane >> 2);
    const int rtab[4] = {0, 1, 2, 0};
    __syncthreads();

    // ---------------- 5 entangling layers: stage A + stage B ----------------
    for (int l = 0; l < 5; ++l) {
        const int g0 = l * 6;
        float e[4];

        if (l == 0) {
            float A = bloch[1][q1] * bloch[2][q2] * bloch[3][q3] * bloch[4][q4] * bloch[5][q5];
            e[0] = A * bloch[0][0];
            e[1] = A * bloch[0][1];
            e[2] = A * bloch[0][2];
            e[3] = A * bloch[0][3];
        } else {
            const int4 te = *(const int4*)&RT.t[rtab[l - 1]][tid << 2];
            float v0 = dmA[swz(te.x & 4095)];
            float v1 = dmA[swz(te.y & 4095)];
            float v2 = dmA[swz(te.z & 4095)];
            float v3 = dmA[swz(te.w & 4095)];
            e[0] = __int_as_float(__float_as_int(v0) ^ (te.x & 0x80000000));
            e[1] = __int_as_float(__float_as_int(v1) ^ (te.y & 0x80000000));
            e[2] = __int_as_float(__float_as_int(v2) ^ (te.z & 0x80000000));
            e[3] = __int_as_float(__float_as_int(v3) ^ (te.w & 0x80000000));
        }
        rot_reg(e, Mlane[g0 + 0][1], Mlane[g0 + 0][2], Mlane[g0 + 0][3]);
        rot_q1(e, Mlane[g0 + 1][q1]);
        rot_q2(e, Mlane[g0 + 2][q2]);
        rot_q3(e, Mlane[g0 + 3][q3], lane);
        *(float4*)&dmB[swz(tid << 2)] = make_float4(e[0], e[1], e[2], e[3]);
        __syncthreads();

        e[0] = dmB[swz(baseB)];
        e[1] = dmB[swz(baseB + 256)];
        e[2] = dmB[swz(baseB + 512)];
        e[3] = dmB[swz(baseB + 768)];
        rot_reg(e, Mlane[g0 + 4][1], Mlane[g0 + 4][2], Mlane[g0 + 4][3]);
        rot_q1(e, Mlane[g0 + 5][lane & 3]);
        dmA[swz(baseB)]       = e[0];
        dmA[swz(baseB + 256)] = e[1];
        dmA[swz(baseB + 512)] = e[2];
        dmA[swz(baseB + 768)] = e[3];
        __syncthreads();
    }

    // ---- readout: fold final ring (r=2 -> table 1) + final dep1 + linear head ----
    if (tid < NQ) {
        int e = RT.t[1][1 << (2 * tid)];
        float v = dmA[swz(e & 4095)];
        v = __int_as_float(__float_as_int(v) ^ (e & 0x80000000));
        evs[tid] = WO1 * v;
    }
    __syncthreads();
    if (tid < 2) {
        float o = bp[tid];
        #pragma unroll
        for (int i = 0; i < NQ; ++i) o = fmaf(evs[i], Wp[tid * NQ + i], o);
        out[b * 2 + tid] = o;
    }
}

extern "C" void kernel_launch(void* const* d_in, const int* in_sizes, int n_in,
                              void* d_out, int out_size, void* d_ws, size_t ws_size,
                              hipStream_t stream) {
    (void)in_sizes; (void)n_in; (void)ws_size; (void)out_size;
    const float* x        = (const float*)d_in[0];
    const float* W1       = (const float*)d_in[1];
    const float* b1       = (const float*)d_in[2];
    const float* ln_g     = (const float*)d_in[3];
    const float* ln_b     = (const float*)d_in[4];
    const float* W2       = (const float*)d_in[5];
    const float* b2       = (const float*)d_in[6];
    const float* shared_w = (const float*)d_in[7];
    const float* task_w   = (const float*)d_in[8];
    const float* Wp       = (const float*)d_in[9];
    const float* bp       = (const float*)d_in[10];
    float* out = (float*)d_out;
    float* hp  = (float*)d_ws;     // 4 * 256 * 256 floats = 1 MB partials

    hipLaunchKernelGGL(enc_gemm, dim3(256), dim3(256), 0, stream, x, W1, hp);
    hipLaunchKernelGGL(nqm_kernel, dim3(256), dim3(BLK), 0, stream,
                       hp, b1, ln_g, ln_b, W2, b2, shared_w, task_w, Wp, bp, out);
}

// Round 9
// 95.248 us; speedup vs baseline: 1.0834x; 1.0030x over previous
//
#include <hip/hip_runtime.h>
#include <math.h>

#define NQ 6
#define BLK 1024
#define HID 256
#define INDIM 784
#define KC 56          // k-chunk (14 float4)
#define NSPLIT 14      // 784 / 56

#define PW1 0.001f
#define PW2 0.01f
constexpr float WO1 = 1.f - 4.f * PW1 / 3.f;   // dep1 Bloch shrink
constexpr float WO2 = 1.f - 4.f * PW2 / 3.f;   // dep2 Bloch shrink
constexpr float WOc = WO1 * WO2;               // combined mid-circuit dep

// ---------- compile-time CNOT-ring tables (inverse map + sign) ----------
// Pauli string: wire w -> bits (x_w at 2w+1, z_w at 2w). Code q=(x<<1)|z: 0=I,1=Z,2=X,3=Y.
// CNOT(c->t): sign ^= x_c z_t (x_t ^ z_c ^ 1); x_t ^= x_c; z_c ^= z_t.
// U^dag P U for ring U = C5..C0 (C0 first): conjugate by C5 first ... C0 last.
struct alignas(16) RingTabs { int t[3][4096]; };
constexpr RingTabs make_ring_tabs() {
    RingTabs R{};
    for (int ri = 0; ri < 3; ++ri) {
        int r = ri + 1;
        for (int v = 0; v < 4096; ++v) {
            int x[6], z[6];
            for (int w = 0; w < 6; ++w) { x[w] = (v >> (2 * w + 1)) & 1; z[w] = (v >> (2 * w)) & 1; }
            int sgn = 0;
            for (int i = 5; i >= 0; --i) {
                int c = i, tg = (i + r) % 6;
                sgn ^= x[c] & z[tg] & (x[tg] ^ z[c] ^ 1);
                x[tg] ^= x[c];
                z[c]  ^= z[tg];
            }
            int s = 0;
            for (int w = 0; w < 6; ++w) s |= (x[w] << (2 * w + 1)) | (z[w] << (2 * w));
            R.t[ri][v] = s | (sgn << 31);
        }
    }
    return R;
}
static __device__ const RingTabs RT = make_ring_tabs();

// LDS bank swizzle: injects n[7:6]^n[11:10] into bank bits [4:3].
__device__ __forceinline__ int swz(int n) {
    return n ^ ((((n >> 6) ^ (n >> 10)) & 3) << 3);
}

// DPP quad broadcasts (quad lane k's value), pure VALU
template<int CTRL>
__device__ __forceinline__ float qb(float v) {
    int r = __builtin_amdgcn_update_dpp(0, __builtin_bit_cast(int, v), CTRL, 0xF, 0xF, true);
    return __builtin_bit_cast(float, r);
}
// ds_swizzle with compile-time pattern
template<int OFF>
__device__ __forceinline__ float swzl(float v) {
    return __builtin_bit_cast(float, __builtin_amdgcn_ds_swizzle(__builtin_bit_cast(int, v), OFF));
}

__device__ __forceinline__ void rot_reg(float e[4], float4 rZ, float4 rX, float4 rY) {
    float X = e[2], Y = e[3], Z = e[1];
    e[2] = fmaf(rX.x, X, fmaf(rX.y, Y, rX.z * Z));
    e[3] = fmaf(rY.x, X, fmaf(rY.y, Y, rY.z * Z));
    e[1] = fmaf(rZ.x, X, fmaf(rZ.y, Y, rZ.z * Z));
}
__device__ __forceinline__ void rot_q1(float e[4], float4 cf) {
    #pragma unroll
    for (int j = 0; j < 4; ++j) {
        float vZ = qb<0x55>(e[j]);
        float vX = qb<0xAA>(e[j]);
        float vY = qb<0xFF>(e[j]);
        e[j] = fmaf(cf.x, vX, fmaf(cf.y, vY, fmaf(cf.z, vZ, cf.w * e[j])));
    }
}
__device__ __forceinline__ void rot_q2(float e[4], float4 cf) {
    #pragma unroll
    for (int j = 0; j < 4; ++j) {
        float vZ = swzl<0x093>(e[j]);
        float vX = swzl<0x113>(e[j]);
        float vY = swzl<0x193>(e[j]);
        e[j] = fmaf(cf.x, vX, fmaf(cf.y, vY, fmaf(cf.z, vZ, cf.w * e[j])));
    }
}
__device__ __forceinline__ void rot_q3(float e[4], float4 cf, int lane) {
    int s1 = (lane & 15) | 16, s2 = (lane & 15) | 32, s3 = (lane & 15) | 48;
    #pragma unroll
    for (int j = 0; j < 4; ++j) {
        float vZ = __shfl(e[j], s1, 64);
        float vX = __shfl(e[j], s2, 64);
        float vY = __shfl(e[j], s3, 64);
        e[j] = fmaf(cf.x, vX, fmaf(cf.y, vY, fmaf(cf.z, vZ, cf.w * e[j])));
    }
}

// ================= kernel A: tiled GEMM partials hp[s][b][u] =================
// 224 blocks = 16 tiles (64b x 64u) x 14 k-splits (56 each). 256 threads, 4x4 micro-tile.
__global__ __launch_bounds__(256)
void enc_gemm(const float* __restrict__ x, const float* __restrict__ W1,
              float* __restrict__ hp)
{
    __shared__ float xsT[KC][64];   // [k][b] transposed
    __shared__ float wsT[KC][64];   // [k][u] transposed
    const int tid = threadIdx.x;
    const int bid = blockIdx.x;
    const int tile = bid / NSPLIT;          // 0..15
    const int s = bid - tile * NSPLIT;      // 0..13
    const int bb = (tile >> 2) * 64;
    const int bu = (tile & 3) * 64;
    const int k0 = s * KC;

    // stage: 2 matrices x 64 rows x 14 float4 = 1792 float4 (7 iters of 256)
    // i -> (r = i&63, cb = i>>6); cb 0..13 = x, 14..27 = W1.
    // LDS writes: wave lanes span 64 distinct r -> 2 lanes/bank (free).
    for (int i = tid; i < 1792; i += 256) {
        int r = i & 63;
        int cb = i >> 6;
        int m = (cb >= 14);
        int c = cb - m * 14;
        const float* src = m ? (W1 + (size_t)(bu + r) * INDIM + k0 + 4 * c)
                             : (x  + (size_t)(bb + r) * INDIM + k0 + 4 * c);
        float4 v = *(const float4*)src;
        float (*dst)[64] = m ? wsT : xsT;
        dst[4 * c + 0][r] = v.x;
        dst[4 * c + 1][r] = v.y;
        dst[4 * c + 2][r] = v.z;
        dst[4 * c + 3][r] = v.w;
    }
    __syncthreads();

    const int tx = tid & 15, ty = tid >> 4;
    float acc[4][4] = {};
    #pragma unroll 7
    for (int k = 0; k < KC; ++k) {
        float4 xv = *(const float4*)&xsT[k][4 * ty];
        float4 wv = *(const float4*)&wsT[k][4 * tx];
        const float xa[4] = {xv.x, xv.y, xv.z, xv.w};
        const float wa[4] = {wv.x, wv.y, wv.z, wv.w};
        #pragma unroll
        for (int i = 0; i < 4; ++i)
            #pragma unroll
            for (int j = 0; j < 4; ++j)
                acc[i][j] = fmaf(xa[i], wa[j], acc[i][j]);
    }
    float* o = hp + (size_t)s * 65536 + (size_t)(bb + 4 * ty) * 256 + bu + 4 * tx;
    #pragma unroll
    for (int i = 0; i < 4; ++i)
        *(float4*)(o + (size_t)i * 256) = make_float4(acc[i][0], acc[i][1], acc[i][2], acc[i][3]);
}

// ================= kernel B: LN + z + circuit (Pauli domain) =================
// Pauli index v = (q5<<10)|(q4<<8)|(q3<<6)|(q2<<4)|(q1<<2)|q0.
// Stage A (wires 0-3, intra-wave): wave=(q5,q4), lane=(q3,q2,q1), regs=q0.
// Stage B (wires 4-5): regs=q4, lane[1:0]=q5, rest=(wave<<4)|lane[5:2].
__global__ __launch_bounds__(BLK)
void nqm_kernel(const float* __restrict__ hp, const float* __restrict__ b1,
                const float* __restrict__ ln_g, const float* __restrict__ ln_b,
                const float* __restrict__ W2, const float* __restrict__ b2,
                const float* __restrict__ shared_w, const float* __restrict__ task_w,
                const float* __restrict__ Wp, const float* __restrict__ bp,
                float* __restrict__ out)
{
    __shared__ __align__(16) float dmA[4096];
    __shared__ __align__(16) float dmB[4096];
    __shared__ __align__(16) float4 Mlane[30][4];
    __shared__ float bloch[NQ][4];
    __shared__ float red[4], red2[4];
    __shared__ float zpart[4][8];
    __shared__ float bcast[2];
    __shared__ float evs[8];

    const int tid = threadIdx.x;
    const int b = blockIdx.x;
    const int wv = tid >> 6;
    const int lane = tid & 63;

    // ---------------- h = relu(sum hp + b1); LayerNorm; z partials ----------------
    float h = 0.0f;
    if (tid < 256) {
        const float* hb = hp + (size_t)b * 256 + tid;
        h = b1[tid];
        #pragma unroll
        for (int s = 0; s < NSPLIT; ++s) h += hb[(size_t)s * 65536];
        h = fmaxf(h, 0.0f);
        float s = h, s2 = h * h;
        #pragma unroll
        for (int off = 32; off > 0; off >>= 1) {
            s  += __shfl_down(s, off, 64);
            s2 += __shfl_down(s2, off, 64);
        }
        if (lane == 0) { red[tid >> 6] = s; red2[tid >> 6] = s2; }
    }
    __syncthreads();
    if (tid == 0) {
        float ts  = red[0] + red[1] + red[2] + red[3];
        float ts2 = red2[0] + red2[1] + red2[2] + red2[3];
        float mu  = ts * (1.0f / HID);
        float var = ts2 * (1.0f / HID) - mu * mu;
        bcast[0] = mu;
        bcast[1] = rsqrtf(var + 1e-5f);
    }
    __syncthreads();
    if (tid < 256) {
        float hnj = (h - bcast[0]) * bcast[1] * ln_g[tid] + ln_b[tid];
        float p[NQ];
        #pragma unroll
        for (int i = 0; i < NQ; ++i) p[i] = hnj * W2[i * HID + tid];
        #pragma unroll
        for (int off = 32; off > 0; off >>= 1) {
            #pragma unroll
            for (int i = 0; i < NQ; ++i) p[i] += __shfl_down(p[i], off, 64);
        }
        if (lane == 0) {
            #pragma unroll
            for (int i = 0; i < NQ; ++i) zpart[tid >> 6][i] = p[i];
        }
    }
    __syncthreads();

    // ------------- gate SO(3) matrices + initial Bloch vectors -------------
    if (tid < NQ) {
        float z = zpart[0][tid] + zpart[1][tid] + zpart[2][tid] + zpart[3][tid] + b2[tid];
        z = tanhf(z);
        float sn, c;
        sincosf(z * 3.14159265358979323846f, &sn, &c);
        bloch[tid][0] = 1.0f;
        bloch[tid][1] = WO1 * c;    // Z
        bloch[tid][2] = WO1 * sn;   // X
        bloch[tid][3] = 0.0f;       // Y
    } else if (tid < 36) {          // threads 6..35 -> gates 0..29
        int g = tid - NQ;
        int layer = g / NQ;
        int wire = g % NQ;
        const float* w = (layer < 3) ? (shared_w + (layer * NQ + wire) * 3)
                                     : (task_w + ((layer - 3) * NQ + wire) * 3);
        float phi = w[0], theta = w[1], omega = w[2];
        float sf, cf_, st, ct, so, co;
        sincosf(phi, &sf, &cf_);
        sincosf(theta, &st, &ct);
        sincosf(omega, &so, &co);
        float M00 = co * ct * cf_ - so * sf;
        float M01 = -co * ct * sf - so * cf_;
        float M02 = co * st;
        float M10 = so * ct * cf_ + co * sf;
        float M11 = -so * ct * sf + co * cf_;
        float M12 = so * st;
        float M20 = -st * cf_;
        float M21 = st * sf;
        float M22 = ct;
        float f = (layer == 3) ? ((wire < 5) ? WOc : WO1) : 1.0f;   // mid-circuit deps baked
        Mlane[g][0] = make_float4(0.f, 0.f, 0.f, 1.f);
        Mlane[g][1] = make_float4(f * M20, f * M21, f * M22, 0.f);
        Mlane[g][2] = make_float4(f * M00, f * M01, f * M02, 0.f);
        Mlane[g][3] = make_float4(f * M10, f * M11, f * M12, 0.f);
    }

    const int q1 = lane & 3, q2 = (lane >> 2) & 3, q3 = (lane >> 4) & 3;
    const int q4 = wv & 3, q5 = wv >> 2;
    const int baseB = ((lane & 3) << 10) | (wv << 4) | (lane >> 2);
    const int rtab[4] = {0, 1, 2, 0};
    __syncthreads();

    // ---------------- 5 entangling layers: stage A + stage B ----------------
    for (int l = 0; l < 5; ++l) {
        const int g0 = l * 6;
        float e[4];

        if (l == 0) {
            float A = bloch[1][q1] * bloch[2][q2] * bloch[3][q3] * bloch[4][q4] * bloch[5][q5];
            e[0] = A * bloch[0][0];
            e[1] = A * bloch[0][1];
            e[2] = A * bloch[0][2];
            e[3] = A * bloch[0][3];
        } else {
            const int4 te = *(const int4*)&RT.t[rtab[l - 1]][tid << 2];
            float v0 = dmA[swz(te.x & 4095)];
            float v1 = dmA[swz(te.y & 4095)];
            float v2 = dmA[swz(te.z & 4095)];
            float v3 = dmA[swz(te.w & 4095)];
            e[0] = __int_as_float(__float_as_int(v0) ^ (te.x & 0x80000000));
            e[1] = __int_as_float(__float_as_int(v1) ^ (te.y & 0x80000000));
            e[2] = __int_as_float(__float_as_int(v2) ^ (te.z & 0x80000000));
            e[3] = __int_as_float(__float_as_int(v3) ^ (te.w & 0x80000000));
        }
        rot_reg(e, Mlane[g0 + 0][1], Mlane[g0 + 0][2], Mlane[g0 + 0][3]);
        rot_q1(e, Mlane[g0 + 1][q1]);
        rot_q2(e, Mlane[g0 + 2][q2]);
        rot_q3(e, Mlane[g0 + 3][q3], lane);
        *(float4*)&dmB[swz(tid << 2)] = make_float4(e[0], e[1], e[2], e[3]);
        __syncthreads();

        e[0] = dmB[swz(baseB)];
        e[1] = dmB[swz(baseB + 256)];
        e[2] = dmB[swz(baseB + 512)];
        e[3] = dmB[swz(baseB + 768)];
        rot_reg(e, Mlane[g0 + 4][1], Mlane[g0 + 4][2], Mlane[g0 + 4][3]);
        rot_q1(e, Mlane[g0 + 5][lane & 3]);
        dmA[swz(baseB)]       = e[0];
        dmA[swz(baseB + 256)] = e[1];
        dmA[swz(baseB + 512)] = e[2];
        dmA[swz(baseB + 768)] = e[3];
        __syncthreads();
    }

    // ---- readout: fold final ring (r=2 -> table 1) + final dep1 + linear head ----
    if (tid < NQ) {
        int e = RT.t[1][1 << (2 * tid)];
        float v = dmA[swz(e & 4095)];
        v = __int_as_float(__float_as_int(v) ^ (e & 0x80000000));
        evs[tid] = WO1 * v;
    }
    __syncthreads();
    if (tid < 2) {
        float o = bp[tid];
        #pragma unroll
        for (int i = 0; i < NQ; ++i) o = fmaf(evs[i], Wp[tid * NQ + i], o);
        out[b * 2 + tid] = o;
    }
}

extern "C" void kernel_launch(void* const* d_in, const int* in_sizes, int n_in,
                              void* d_out, int out_size, void* d_ws, size_t ws_size,
                              hipStream_t stream) {
    (void)in_sizes; (void)n_in; (void)ws_size; (void)out_size;
    const float* x        = (const float*)d_in[0];
    const float* W1       = (const float*)d_in[1];
    const float* b1       = (const float*)d_in[2];
    const float* ln_g     = (const float*)d_in[3];
    const float* ln_b     = (const float*)d_in[4];
    const float* W2       = (const float*)d_in[5];
    const float* b2       = (const float*)d_in[6];
    const float* shared_w = (const float*)d_in[7];
    const float* task_w   = (const float*)d_in[8];
    const float* Wp       = (const float*)d_in[9];
    const float* bp       = (const float*)d_in[10];
    float* out = (float*)d_out;
    float* hp  = (float*)d_ws;     // 14 * 256 * 256 floats = 3.67 MB partials

    hipLaunchKernelGGL(enc_gemm, dim3(16 * NSPLIT), dim3(256), 0, stream, x, W1, hp);
    hipLaunchKernelGGL(nqm_kernel, dim3(256), dim3(BLK), 0, stream,
                       hp, b1, ln_g, ln_b, W2, b2, shared_w, task_w, Wp, bp, out);
}